// Round 16
// baseline (173.284 us; speedup 1.0000x reference)
//
#include <hip/hip_runtime.h>
#include <stdint.h>

#define BB 16384
#define PR2 16896     // 16384 + 8*64 worst-case bucket padding (64-granular)
#define MAXT2 264     // PR2/64 = 8*33

typedef short bf16x8 __attribute__((ext_vector_type(8)));
typedef float f32x4 __attribute__((ext_vector_type(4)));

typedef __attribute__((address_space(1))) unsigned short gus_t;
typedef __attribute__((address_space(3))) unsigned short lus_t;

__device__ __forceinline__ unsigned short f2bf(float f) {
    unsigned int u = __float_as_uint(f);
    u += 0x7fffu + ((u >> 16) & 1u);   // RNE
    return (unsigned short)(u >> 16);
}
__device__ __forceinline__ float bf2f(unsigned short h) {
    return __uint_as_float(((unsigned int)h) << 16);
}

__device__ __forceinline__ void gld16(const unsigned short* g, unsigned short* l) {
    __builtin_amdgcn_global_load_lds(
        reinterpret_cast<const gus_t*>(reinterpret_cast<uintptr_t>(g)),
        reinterpret_cast<lus_t*>(reinterpret_cast<uintptr_t>(l)),
        16, 0, 0);
}

#define GLOAD(dst_, ptr_) \
    asm volatile("global_load_dwordx4 %0, %1, off" : "=v"(dst_) : "v"(ptr_) : "memory")

// ---------------- transposing weight conversion ----------------
// Wt[li][ks][col][kg] (16B granules) <- W[li][col][ks*32+kg*8 .. +8]  (f32 -> bf16)
__global__ __launch_bounds__(256) void cvt_wt(const float* __restrict__ dec_W,
                                              const float* __restrict__ exp_W,
                                              unsigned short* __restrict__ dst) {
    const int g = blockIdx.x * 256 + threadIdx.x;   // 36*32768 granules exactly
    const int li = g >> 15;
    const int r = g & 32767;
    const int col = r >> 6;
    const int ks = (r >> 2) & 15;
    const int kg = r & 3;
    const float* src = (li < 4 ? dec_W + ((size_t)li << 18)
                               : exp_W + ((size_t)(li - 4) << 18))
                     + (col << 9) + (ks << 5) + (kg << 3);
    f32x4 v0 = *reinterpret_cast<const f32x4*>(src);
    f32x4 v1 = *reinterpret_cast<const f32x4*>(src + 4);
    bf16x8 o;
#pragma unroll
    for (int q = 0; q < 4; ++q) { o[q] = (short)f2bf(v0[q]); o[q + 4] = (short)f2bf(v1[q]); }
    *reinterpret_cast<bf16x8*>(dst + ((size_t)li << 18) + (ks << 14) + (col << 5) + (kg << 3)) = o;
}

// ---------------- bucketing (64-granular, block-aggregated atomics) ----------------
__global__ __launch_bounds__(1024) void bucket_count(const int* __restrict__ y, int* counts) {
    __shared__ int lc[8];
    const int t = threadIdx.x;
    if (t < 8) lc[t] = 0;
    __syncthreads();
    atomicAdd(&lc[y[blockIdx.x * 1024 + t]], 1);
    __syncthreads();
    if (t < 8) atomicAdd(&counts[t], lc[t]);
}

__global__ void bucket_scan(const int* __restrict__ counts, int* starts, int* tile_exp) {
    if (threadIdx.x == 0 && blockIdx.x == 0) {
        int s = 0;
        for (int e = 0; e < 8; ++e) {
            starts[e] = s;
            int nt = (counts[e] + 63) >> 6;
            for (int t = 0; t < nt; ++t) tile_exp[(s >> 6) + t] = e;
            s += nt << 6;
        }
        starts[8] = s;
    }
}

__global__ __launch_bounds__(1024) void bucket_scatter(const int* __restrict__ y,
                                                       const int* __restrict__ starts,
                                                       int* cursors, int* perm) {
    __shared__ int lc[8];
    __shared__ int lbase[8];
    const int t = threadIdx.x;
    if (t < 8) lc[t] = 0;
    __syncthreads();
    const int i = blockIdx.x * 1024 + t;
    const int e = y[i];
    const int r = atomicAdd(&lc[e], 1);
    __syncthreads();
    if (t < 8) lbase[t] = atomicAdd(&cursors[t], lc[t]);
    __syncthreads();
    perm[starts[e] + lbase[e] + r] = i;
}

// ---------------- fused 4-layer MLP (R15 base: K-step 64, verified) ----------------
// Each ITER consumes a full 64-elem k-block (even+odd chunk), 16 MFMAs, one 4-load W
// set; 32 steps total (8/layer). bv 2-set rotation, vmcnt(4) steady. + T5 setprio
// around the MFMA cluster (decoupled waves = role-diverse regime, m191-positive).
template <int PHASE>
__global__ __launch_bounds__(1024) void fused4(
    const float* __restrict__ sf32,
    const unsigned short* __restrict__ srelg,
    const unsigned short* __restrict__ Wb,      // transposed Wt layout base
    const float* __restrict__ biasb,
    unsigned short* __restrict__ srel_out,
    unsigned short* __restrict__ h_out,
    const unsigned short* __restrict__ h_in,
    float* __restrict__ outf,
    const int* __restrict__ perm,
    const int* __restrict__ tile_exp,
    const int* __restrict__ starts8)
{
    __shared__ __align__(16) unsigned short ls[32768];   // 64 KB: A tile only

    const int bid = blockIdx.x;
    int tile;
    if (PHASE == 0) {
        tile = ((bid & 7) << 5) + (bid >> 3);             // XCD swizzle, 256 = 8*32
    } else {
        tile = (bid & 7) * 33 + (bid >> 3);               // XCD swizzle, 264 = 8*33
        if ((tile << 6) >= starts8[0]) return;
    }

    const unsigned short* Wl;
    const float* bl;
    if (PHASE == 0) { Wl = Wb; bl = biasb; }
    else {
        const int e = tile_exp[tile];
        Wl = Wb + ((size_t)e << 20);
        bl = biasb + (e << 11);
    }

    const int t = threadIdx.x;
    const int w = t >> 6;                                 // 0..15
    const int lane = t & 63;
    const int lr = lane & 15;
    const int kg = lane >> 4;
    const int off = ((tile * 3) + w) & 7;                 // per-wave K-stagger (8 steps/layer)

    const int ac = (t & 56) | ((t ^ w) & 7);              // A stage src chunk (inv-swizzle)
    const int axor = lr & 7;
    const int arow0 = (lr) << 9;
    const int arow1 = ((16 + lr)) << 9;
    const int arow2 = ((32 + lr)) << 9;
    const int arow3 = ((48 + lr)) << 9;
    const int klo_e = ((kg ^ axor) << 3);                 // even chunk in-row offset
    const int klo_o = (((4 | kg) ^ axor) << 3);           // odd chunk in-row offset

    const unsigned short* wpt0 = Wl + ((((w << 5) + lr)) << 5) + (kg << 3);
    const unsigned short* wpt1 = wpt0 + 512;

    float bball[8];
#pragma unroll
    for (int l = 0; l < 4; ++l) {
        bball[(l << 1) + 0] = bl[(l << 9) + (w << 5) + lr];
        bball[(l << 1) + 1] = bl[(l << 9) + (w << 5) + 16 + lr];
    }

    if (PHASE == 0) {
#pragma unroll
        for (int c4 = 0; c4 < 4; ++c4) {
            const int grow = (tile << 6) + (c4 << 4) + w;
            const float* sp = sf32 + (((size_t)grow) << 9) + (ac << 3);
            f32x4 v0 = *reinterpret_cast<const f32x4*>(sp);
            f32x4 v1 = *reinterpret_cast<const f32x4*>(sp + 4);
            bf16x8 o;
#pragma unroll
            for (int q = 0; q < 4; ++q) { o[q] = (short)f2bf(v0[q]); o[q + 4] = (short)f2bf(v1[q]); }
            *reinterpret_cast<bf16x8*>(&ls[(c4 << 13) + (t << 3)]) = o;
        }
    } else {
#pragma unroll
        for (int c4 = 0; c4 < 4; ++c4) {
            int pr = perm[(tile << 6) + (c4 << 4) + w];
            if (pr < 0) pr = 0;
            gld16(srelg + (((size_t)pr) << 9) + (ac << 3), ls + (c4 << 13) + (t << 3));
        }
    }

    // ---- W prologue: sets for steps 0 and 1 (8 loads in flight) ----
    bf16x8 bvA[4], bvB[4];
    {
        const size_t x0 = ((size_t)(off & 7)) << 15;
        const size_t x1 = ((size_t)((1 + off) & 7)) << 15;
        GLOAD(bvA[0], wpt0 + x0);         GLOAD(bvA[1], wpt1 + x0);
        GLOAD(bvA[2], wpt0 + x0 + 16384); GLOAD(bvA[3], wpt1 + x0 + 16384);
        GLOAD(bvB[0], wpt0 + x1);         GLOAD(bvB[1], wpt1 + x1);
        GLOAD(bvB[2], wpt0 + x1 + 16384); GLOAD(bvB[3], wpt1 + x1 + 16384);
    }
    if (PHASE == 0) {
        asm volatile("s_waitcnt lgkmcnt(0)" ::: "memory");   // my A ds_writes done
    } else {
        asm volatile("s_waitcnt vmcnt(8)" ::: "memory");     // A DMA done (8 W in flight)
    }
    __builtin_amdgcn_s_barrier();                            // A visible to all waves

    f32x4 acc[4][2];
#pragma unroll
    for (int m = 0; m < 4; ++m) { acc[m][0] = f32x4{0,0,0,0}; acc[m][1] = f32x4{0,0,0,0}; }

#define ITER(s_, bvS) do {                                                         \
    if ((s_) < 31) asm volatile("s_waitcnt vmcnt(4)" ::: "memory");                \
    else           asm volatile("s_waitcnt vmcnt(0)" ::: "memory");                \
    __builtin_amdgcn_sched_barrier(0);                                             \
    {                                                                              \
        const int st_ = (((s_) & 7) + off) & 7;                                    \
        const int sb_ = st_ << 6;                                                  \
        bf16x8 ae0 = *reinterpret_cast<const bf16x8*>(&ls[arow0 + sb_ + klo_e]);   \
        bf16x8 ae1 = *reinterpret_cast<const bf16x8*>(&ls[arow1 + sb_ + klo_e]);   \
        bf16x8 ae2 = *reinterpret_cast<const bf16x8*>(&ls[arow2 + sb_ + klo_e]);   \
        bf16x8 ae3 = *reinterpret_cast<const bf16x8*>(&ls[arow3 + sb_ + klo_e]);   \
        __builtin_amdgcn_s_setprio(1);                                             \
        acc[0][0] = __builtin_amdgcn_mfma_f32_16x16x32_bf16(ae0, bvS[0], acc[0][0], 0, 0, 0); \
        acc[0][1] = __builtin_amdgcn_mfma_f32_16x16x32_bf16(ae0, bvS[1], acc[0][1], 0, 0, 0); \
        acc[1][0] = __builtin_amdgcn_mfma_f32_16x16x32_bf16(ae1, bvS[0], acc[1][0], 0, 0, 0); \
        acc[1][1] = __builtin_amdgcn_mfma_f32_16x16x32_bf16(ae1, bvS[1], acc[1][1], 0, 0, 0); \
        acc[2][0] = __builtin_amdgcn_mfma_f32_16x16x32_bf16(ae2, bvS[0], acc[2][0], 0, 0, 0); \
        acc[2][1] = __builtin_amdgcn_mfma_f32_16x16x32_bf16(ae2, bvS[1], acc[2][1], 0, 0, 0); \
        acc[3][0] = __builtin_amdgcn_mfma_f32_16x16x32_bf16(ae3, bvS[0], acc[3][0], 0, 0, 0); \
        acc[3][1] = __builtin_amdgcn_mfma_f32_16x16x32_bf16(ae3, bvS[1], acc[3][1], 0, 0, 0); \
        __builtin_amdgcn_s_setprio(0);                                             \
        bf16x8 ao0 = *reinterpret_cast<const bf16x8*>(&ls[arow0 + sb_ + klo_o]);   \
        bf16x8 ao1 = *reinterpret_cast<const bf16x8*>(&ls[arow1 + sb_ + klo_o]);   \
        bf16x8 ao2 = *reinterpret_cast<const bf16x8*>(&ls[arow2 + sb_ + klo_o]);   \
        bf16x8 ao3 = *reinterpret_cast<const bf16x8*>(&ls[arow3 + sb_ + klo_o]);   \
        __builtin_amdgcn_s_setprio(1);                                             \
        acc[0][0] = __builtin_amdgcn_mfma_f32_16x16x32_bf16(ao0, bvS[2], acc[0][0], 0, 0, 0); \
        acc[0][1] = __builtin_amdgcn_mfma_f32_16x16x32_bf16(ao0, bvS[3], acc[0][1], 0, 0, 0); \
        acc[1][0] = __builtin_amdgcn_mfma_f32_16x16x32_bf16(ao1, bvS[2], acc[1][0], 0, 0, 0); \
        acc[1][1] = __builtin_amdgcn_mfma_f32_16x16x32_bf16(ao1, bvS[3], acc[1][1], 0, 0, 0); \
        acc[2][0] = __builtin_amdgcn_mfma_f32_16x16x32_bf16(ao2, bvS[2], acc[2][0], 0, 0, 0); \
        acc[2][1] = __builtin_amdgcn_mfma_f32_16x16x32_bf16(ao2, bvS[3], acc[2][1], 0, 0, 0); \
        acc[3][0] = __builtin_amdgcn_mfma_f32_16x16x32_bf16(ao3, bvS[2], acc[3][0], 0, 0, 0); \
        acc[3][1] = __builtin_amdgcn_mfma_f32_16x16x32_bf16(ao3, bvS[3], acc[3][1], 0, 0, 0); \
        __builtin_amdgcn_s_setprio(0);                                             \
    }                                                                              \
    if ((s_) + 2 < 32) {                                                           \
        const int l2_ = ((s_) + 2) >> 3;                                           \
        const int st2_ = ((((s_) + 2) & 7) + off) & 7;                             \
        const size_t x_ = (((size_t)l2_) << 18) + (((size_t)st2_) << 15);          \
        GLOAD(bvS[0], wpt0 + x_);         GLOAD(bvS[1], wpt1 + x_);                \
        GLOAD(bvS[2], wpt0 + x_ + 16384); GLOAD(bvS[3], wpt1 + x_ + 16384);        \
    }                                                                              \
    if (((s_) & 7) == 7 && (s_) < 31) {                                            \
        __builtin_amdgcn_s_barrier();        /* all waves done reading A */        \
        const int lb_ = ((s_) >> 3) << 1;                                          \
        _Pragma("unroll")                                                          \
        for (int m = 0; m < 4; ++m)                                                \
            _Pragma("unroll")                                                      \
            for (int j = 0; j < 2; ++j) {                                          \
                _Pragma("unroll")                                                  \
                for (int reg = 0; reg < 4; ++reg) {                                \
                    const int row_ = (m << 4) + (kg << 2) + reg;                   \
                    const float v_ = fmaxf(acc[m][j][reg] + bball[lb_ + j], 0.f);  \
                    const int c_ = (w << 2) + (j << 1) + (lr >> 3);                \
                    const int slot_ = (c_ & 56) | ((c_ ^ row_) & 7);               \
                    ls[(row_ << 9) + (slot_ << 3) + (lr & 7)] = f2bf(v_);          \
                }                                                                  \
                acc[m][j] = f32x4{0, 0, 0, 0};                                     \
            }                                                                      \
        asm volatile("s_waitcnt lgkmcnt(0)" ::: "memory");                         \
        __builtin_amdgcn_s_barrier();                                              \
    }                                                                              \
} while (0)

    for (int sp = 0; sp < 16; ++sp) {
        const int s0 = sp << 1;
        ITER(s0, bvA);
        ITER(s0 + 1, bvB);
    }
#undef ITER

    // ---- final epilogue (bball[6..7] = layer-3 bias) ----
    if (PHASE == 0) {
        __syncthreads();
#pragma unroll
        for (int m = 0; m < 4; ++m)
#pragma unroll
            for (int j = 0; j < 2; ++j)
#pragma unroll
                for (int reg = 0; reg < 4; ++reg) {
                    const int row = (m << 4) + (kg << 2) + reg;
                    const int col = (w << 5) + (j << 4) + lr;
                    const float h = fmaxf(acc[m][j][reg] + bball[6 + j], 0.f);
                    const float sv = sf32[(((size_t)((tile << 6) + row)) << 9) + col];
                    const int c = (w << 2) + (j << 1) + (lr >> 3);
                    const int slot = (c & 56) | ((c ^ row) & 7);
                    ls[(row << 9) + (slot << 3) + (lr & 7)] = f2bf(sv - h);
                }
        __syncthreads();
#pragma unroll
        for (int c4 = 0; c4 < 4; ++c4) {
            const int row = (c4 << 4) + w;
            const size_t go = (((size_t)((tile << 6) + row)) << 9) + (ac << 3);
            *reinterpret_cast<bf16x8*>(&srel_out[go]) =
                *reinterpret_cast<const bf16x8*>(&ls[(c4 << 13) + (t << 3)]);
        }
        __syncthreads();
#pragma unroll
        for (int m = 0; m < 4; ++m)
#pragma unroll
            for (int j = 0; j < 2; ++j)
#pragma unroll
                for (int reg = 0; reg < 4; ++reg) {
                    const int row = (m << 4) + (kg << 2) + reg;
                    const float h = fmaxf(acc[m][j][reg] + bball[6 + j], 0.f);
                    const int c = (w << 2) + (j << 1) + (lr >> 3);
                    const int slot = (c & 56) | ((c ^ row) & 7);
                    ls[(row << 9) + (slot << 3) + (lr & 7)] = f2bf(h);
                }
        __syncthreads();
#pragma unroll
        for (int c4 = 0; c4 < 4; ++c4) {
            const int row = (c4 << 4) + w;
            const size_t go = (((size_t)((tile << 6) + row)) << 9) + (ac << 3);
            *reinterpret_cast<bf16x8*>(&h_out[go]) =
                *reinterpret_cast<const bf16x8*>(&ls[(c4 << 13) + (t << 3)]);
        }
    } else {
#pragma unroll
        for (int m = 0; m < 4; ++m) {
#pragma unroll
            for (int reg = 0; reg < 4; ++reg) {
                const int row = (m << 4) + (kg << 2) + reg;
                const int pr = perm[(tile << 6) + row];
                if (pr >= 0) {
#pragma unroll
                    for (int j = 0; j < 2; ++j) {
                        const int col = (w << 5) + (j << 4) + lr;
                        const size_t gi = (((size_t)pr) << 9) + col;
                        outf[gi] = acc[m][j][reg] + bball[6 + j] + bf2f(h_in[gi]);
                    }
                }
            }
        }
    }
}

// ---------------- launch ----------------
extern "C" void kernel_launch(void* const* d_in, const int* in_sizes, int n_in,
                              void* d_out, int out_size, void* d_ws, size_t ws_size,
                              hipStream_t stream)
{
    const float* s     = (const float*)d_in[0];
    const int*   y     = (const int*)d_in[1];
    const float* dec_W = (const float*)d_in[2];
    const float* dec_b = (const float*)d_in[3];
    const float* exp_W = (const float*)d_in[4];
    const float* exp_b = (const float*)d_in[5];
    float* out = (float*)d_out;

    unsigned short* Wt   = (unsigned short*)d_ws;               // 36*262144 bf16, transposed
    unsigned short* srel = Wt + (size_t)36 * 262144;            // BB*512 bf16
    unsigned short* hbuf = srel + (size_t)BB * 512;             // BB*512 bf16
    int* perm     = (int*)(hbuf + (size_t)BB * 512);            // PR2
    int* counts   = perm + PR2;                                 // 8
    int* cursors  = counts + 8;                                 // 8
    int* starts   = cursors + 8;                                // 9
    int* tile_exp = starts + 9;                                 // MAXT2

    cvt_wt<<<4608, 256, 0, stream>>>(dec_W, exp_W, Wt);

    // init via DMA engine: perm = -1 (0xFF bytes); counts/cursors/starts/tile_exp = 0
    hipMemsetAsync(perm, 0xFF, (size_t)PR2 * sizeof(int), stream);
    hipMemsetAsync(counts, 0, (size_t)(8 + 8 + 9 + MAXT2) * sizeof(int), stream);

    bucket_count<<<BB / 1024, 1024, 0, stream>>>(y, counts);
    bucket_scan<<<1, 64, 0, stream>>>(counts, starts, tile_exp);
    bucket_scatter<<<BB / 1024, 1024, 0, stream>>>(y, starts, cursors, perm);

    fused4<0><<<256, 1024, 0, stream>>>(s, nullptr, Wt, dec_b, srel, hbuf,
                                        nullptr, nullptr, nullptr, nullptr, nullptr);
    fused4<1><<<MAXT2, 1024, 0, stream>>>(nullptr, srel, Wt + ((size_t)4 << 18), exp_b,
                                          nullptr, nullptr, hbuf, out,
                                          perm, tile_exp, starts + 8);
}

// Round 18
// 164.090 us; speedup vs baseline: 1.0560x; 1.0560x over previous
//
#include <hip/hip_runtime.h>
#include <stdint.h>

#define BB 16384
#define PR2 16896     // 16384 + 8*64 worst-case bucket padding (64-granular)
#define MAXT2 264     // PR2/64 = 8*33

typedef short bf16x8 __attribute__((ext_vector_type(8)));
typedef float f32x4 __attribute__((ext_vector_type(4)));

typedef __attribute__((address_space(1))) unsigned short gus_t;
typedef __attribute__((address_space(3))) unsigned short lus_t;

__device__ __forceinline__ unsigned short f2bf(float f) {
    unsigned int u = __float_as_uint(f);
    u += 0x7fffu + ((u >> 16) & 1u);   // RNE
    return (unsigned short)(u >> 16);
}
__device__ __forceinline__ float bf2f(unsigned short h) {
    return __uint_as_float(((unsigned int)h) << 16);
}

__device__ __forceinline__ void gld16(const unsigned short* g, unsigned short* l) {
    __builtin_amdgcn_global_load_lds(
        reinterpret_cast<const gus_t*>(reinterpret_cast<uintptr_t>(g)),
        reinterpret_cast<lus_t*>(reinterpret_cast<uintptr_t>(l)),
        16, 0, 0);
}

#define GLOAD(dst_, ptr_) \
    asm volatile("global_load_dwordx4 %0, %1, off" : "=v"(dst_) : "v"(ptr_) : "memory")

// ---------------- transposing weight conversion ----------------
// Wt[li][ks][col][kg] (16B granules) <- W[li][col][ks*32+kg*8 .. +8]  (f32 -> bf16)
__global__ __launch_bounds__(256) void cvt_wt(const float* __restrict__ dec_W,
                                              const float* __restrict__ exp_W,
                                              unsigned short* __restrict__ dst) {
    const int g = blockIdx.x * 256 + threadIdx.x;   // 36*32768 granules exactly
    const int li = g >> 15;
    const int r = g & 32767;
    const int col = r >> 6;
    const int ks = (r >> 2) & 15;
    const int kg = r & 3;
    const float* src = (li < 4 ? dec_W + ((size_t)li << 18)
                               : exp_W + ((size_t)(li - 4) << 18))
                     + (col << 9) + (ks << 5) + (kg << 3);
    f32x4 v0 = *reinterpret_cast<const f32x4*>(src);
    f32x4 v1 = *reinterpret_cast<const f32x4*>(src + 4);
    bf16x8 o;
#pragma unroll
    for (int q = 0; q < 4; ++q) { o[q] = (short)f2bf(v0[q]); o[q + 4] = (short)f2bf(v1[q]); }
    *reinterpret_cast<bf16x8*>(dst + ((size_t)li << 18) + (ks << 14) + (col << 5) + (kg << 3)) = o;
}

// ---------------- bucketing (64-granular, block-aggregated atomics) ----------------
__global__ void bucket_init(int* perm, int* counts, int* cursors, int* tile_exp) {
    int i = blockIdx.x * blockDim.x + threadIdx.x;
    if (i < PR2) perm[i] = -1;
    if (i < 8) { counts[i] = 0; cursors[i] = 0; }
    if (i < MAXT2) tile_exp[i] = 0;
}

__global__ __launch_bounds__(1024) void bucket_count(const int* __restrict__ y, int* counts) {
    __shared__ int lc[8];
    const int t = threadIdx.x;
    if (t < 8) lc[t] = 0;
    __syncthreads();
    atomicAdd(&lc[y[blockIdx.x * 1024 + t]], 1);
    __syncthreads();
    if (t < 8) atomicAdd(&counts[t], lc[t]);
}

__global__ void bucket_scan(const int* __restrict__ counts, int* starts, int* tile_exp) {
    if (threadIdx.x == 0 && blockIdx.x == 0) {
        int s = 0;
        for (int e = 0; e < 8; ++e) {
            starts[e] = s;
            int nt = (counts[e] + 63) >> 6;
            for (int t = 0; t < nt; ++t) tile_exp[(s >> 6) + t] = e;
            s += nt << 6;
        }
        starts[8] = s;
    }
}

__global__ __launch_bounds__(1024) void bucket_scatter(const int* __restrict__ y,
                                                       const int* __restrict__ starts,
                                                       int* cursors, int* perm) {
    __shared__ int lc[8];
    __shared__ int lbase[8];
    const int t = threadIdx.x;
    if (t < 8) lc[t] = 0;
    __syncthreads();
    const int i = blockIdx.x * 1024 + t;
    const int e = y[i];
    const int r = atomicAdd(&lc[e], 1);
    __syncthreads();
    if (t < 8) lbase[t] = atomicAdd(&cursors[t], lc[t]);
    __syncthreads();
    perm[starts[e] + lbase[e] + r] = i;
}

// ---------------- fused 4-layer MLP: A in LDS (64 KB), W global->VGPR ----------------
// Verified best (R11, 164.7us total). 1024 threads / 16 waves; wave w owns all 64 rows
// x cols [w*32, w*32+32); acc[4][2]. No W-LDS, no per-step barriers (only 3 layer
// boundaries + epilogue). W loaded per-iter via 2 asm GLOADs x 2 halves (2-set
// rotation, vmcnt(2)). A-LDS layout: chunk c of row r at slot (c&56)|((c^r)&7).
#define MFMA8(afX, bvX)                                                              \
    acc[0][0] = __builtin_amdgcn_mfma_f32_16x16x32_bf16(afX##0, bvX[0], acc[0][0], 0, 0, 0); \
    acc[0][1] = __builtin_amdgcn_mfma_f32_16x16x32_bf16(afX##0, bvX[1], acc[0][1], 0, 0, 0); \
    acc[1][0] = __builtin_amdgcn_mfma_f32_16x16x32_bf16(afX##1, bvX[0], acc[1][0], 0, 0, 0); \
    acc[1][1] = __builtin_amdgcn_mfma_f32_16x16x32_bf16(afX##1, bvX[1], acc[1][1], 0, 0, 0); \
    acc[2][0] = __builtin_amdgcn_mfma_f32_16x16x32_bf16(afX##2, bvX[0], acc[2][0], 0, 0, 0); \
    acc[2][1] = __builtin_amdgcn_mfma_f32_16x16x32_bf16(afX##2, bvX[1], acc[2][1], 0, 0, 0); \
    acc[3][0] = __builtin_amdgcn_mfma_f32_16x16x32_bf16(afX##3, bvX[0], acc[3][0], 0, 0, 0); \
    acc[3][1] = __builtin_amdgcn_mfma_f32_16x16x32_bf16(afX##3, bvX[1], acc[3][1], 0, 0, 0);

template <int PHASE>
__global__ __launch_bounds__(1024) void fused4(
    const float* __restrict__ sf32,
    const unsigned short* __restrict__ srelg,
    const unsigned short* __restrict__ Wb,      // transposed layout base
    const float* __restrict__ biasb,
    unsigned short* __restrict__ srel_out,
    unsigned short* __restrict__ h_out,
    const unsigned short* __restrict__ h_in,
    float* __restrict__ outf,
    const int* __restrict__ perm,
    const int* __restrict__ tile_exp,
    const int* __restrict__ starts8)
{
    __shared__ __align__(16) unsigned short ls[32768];   // 64 KB: A tile only

    const int bid = blockIdx.x;
    int tile;
    if (PHASE == 0) {
        tile = ((bid & 7) << 5) + (bid >> 3);             // XCD swizzle, 256 = 8*32
    } else {
        tile = (bid & 7) * 33 + (bid >> 3);               // XCD swizzle, 264 = 8*33
        if ((tile << 6) >= starts8[0]) return;
    }

    const unsigned short* Wl;
    const float* bl;
    if (PHASE == 0) { Wl = Wb; bl = biasb; }
    else {
        const int e = tile_exp[tile];
        Wl = Wb + ((size_t)e << 20);                      // e*4*262144 elems
        bl = biasb + (e << 11);
    }

    const int t = threadIdx.x;
    const int w = t >> 6;                                 // 0..15
    const int lane = t & 63;
    const int lr = lane & 15;
    const int kg = lane >> 4;
    const int off = ((tile * 3) + w) & 15;                // per-wave K-stagger

    const int ac = (t & 56) | ((t ^ w) & 7);              // A stage src chunk (inv-swizzle)
    const int axor = lr & 7;
    const int arow0 = (lr) << 9;
    const int arow1 = ((16 + lr)) << 9;
    const int arow2 = ((32 + lr)) << 9;
    const int arow3 = ((48 + lr)) << 9;

    // per-lane W fragment base (transposed layout): col*32 + kg*8 elems
    const unsigned short* wpt0 = Wl + ((((w << 5) + lr)) << 5) + (kg << 3);
    const unsigned short* wpt1 = wpt0 + 512;              // col + 16

    // ---- biases for all 4 layers (2 cols/wave-thread) ----
    float bball[8];
#pragma unroll
    for (int l = 0; l < 4; ++l) {
        bball[(l << 1) + 0] = bl[(l << 9) + (w << 5) + lr];
        bball[(l << 1) + 1] = bl[(l << 9) + (w << 5) + 16 + lr];
    }

    // ---- initial A stage ----
    if (PHASE == 0) {
#pragma unroll
        for (int c4 = 0; c4 < 4; ++c4) {
            const int grow = (tile << 6) + (c4 << 4) + w;
            const float* sp = sf32 + (((size_t)grow) << 9) + (ac << 3);
            f32x4 v0 = *reinterpret_cast<const f32x4*>(sp);
            f32x4 v1 = *reinterpret_cast<const f32x4*>(sp + 4);
            bf16x8 o;
#pragma unroll
            for (int q = 0; q < 4; ++q) { o[q] = (short)f2bf(v0[q]); o[q + 4] = (short)f2bf(v1[q]); }
            *reinterpret_cast<bf16x8*>(&ls[(c4 << 13) + (t << 3)]) = o;
        }
    } else {
#pragma unroll
        for (int c4 = 0; c4 < 4; ++c4) {
            int pr = perm[(tile << 6) + (c4 << 4) + w];
            if (pr < 0) pr = 0;
            gld16(srelg + (((size_t)pr) << 9) + (ac << 3), ls + (c4 << 13) + (t << 3));
        }
    }

    // ---- W register prologue: sets for steps 0 and 1 ----
    bf16x8 bv0[2], bv1[2];
    {
        const size_t l0 = ((size_t)(off & 15)) << 14;
        const size_t l1 = ((size_t)((1 + off) & 15)) << 14;
        GLOAD(bv0[0], wpt0 + l0); GLOAD(bv0[1], wpt1 + l0);
        GLOAD(bv1[0], wpt0 + l1); GLOAD(bv1[1], wpt1 + l1);
    }
    if (PHASE == 0) {
        asm volatile("s_waitcnt lgkmcnt(0)" ::: "memory");   // my A ds_writes done
    } else {
        asm volatile("s_waitcnt vmcnt(4)" ::: "memory");     // A DMA done (W still in flight)
    }
    __builtin_amdgcn_s_barrier();                            // A visible to all waves

    f32x4 acc[4][2];
#pragma unroll
    for (int m = 0; m < 4; ++m) { acc[m][0] = f32x4{0,0,0,0}; acc[m][1] = f32x4{0,0,0,0}; }

#define ITER(s_, bvS) do {                                                         \
    if ((s_) < 62) asm volatile("s_waitcnt vmcnt(2)" ::: "memory");                \
    else           asm volatile("s_waitcnt vmcnt(0)" ::: "memory");                \
    __builtin_amdgcn_sched_barrier(0);                                             \
    {                                                                              \
        const int st_ = (((s_) & 15) + off) & 15;                                  \
        const int sb_ = (st_ >> 1) << 6;                                           \
        const int klo_ = ((((st_ & 1) << 2) | kg) ^ axor) << 3;                    \
        bf16x8 af_0 = *reinterpret_cast<const bf16x8*>(&ls[arow0 + sb_ + klo_]);   \
        bf16x8 af_1 = *reinterpret_cast<const bf16x8*>(&ls[arow1 + sb_ + klo_]);   \
        bf16x8 af_2 = *reinterpret_cast<const bf16x8*>(&ls[arow2 + sb_ + klo_]);   \
        bf16x8 af_3 = *reinterpret_cast<const bf16x8*>(&ls[arow3 + sb_ + klo_]);   \
        MFMA8(af_, bvS)                                                            \
    }                                                                              \
    if ((s_) + 2 < 64) {                                                           \
        const size_t lofs_ = (((size_t)(((s_) + 2) >> 4)) << 18)                   \
                           + (((size_t)(((((s_) + 2) & 15) + off) & 15)) << 14);   \
        GLOAD(bvS[0], wpt0 + lofs_);                                               \
        GLOAD(bvS[1], wpt1 + lofs_);                                               \
    }                                                                              \
    if (((s_) & 15) == 15 && (s_) < 63) {                                          \
        __builtin_amdgcn_s_barrier();        /* all waves done reading A */        \
        const int lb_ = ((s_) >> 4) << 1;                                          \
        _Pragma("unroll")                                                          \
        for (int m = 0; m < 4; ++m)                                                \
            _Pragma("unroll")                                                      \
            for (int j = 0; j < 2; ++j) {                                          \
                _Pragma("unroll")                                                  \
                for (int reg = 0; reg < 4; ++reg) {                                \
                    const int row_ = (m << 4) + (kg << 2) + reg;                   \
                    const float v_ = fmaxf(acc[m][j][reg] + bball[lb_ + j], 0.f);  \
                    const int c_ = (w << 2) + (j << 1) + (lr >> 3);                \
                    const int slot_ = (c_ & 56) | ((c_ ^ row_) & 7);               \
                    ls[(row_ << 9) + (slot_ << 3) + (lr & 7)] = f2bf(v_);          \
                }                                                                  \
                acc[m][j] = f32x4{0, 0, 0, 0};                                     \
            }                                                                      \
        asm volatile("s_waitcnt lgkmcnt(0)" ::: "memory");                         \
        __builtin_amdgcn_s_barrier();                                              \
    }                                                                              \
} while (0)

    for (int sp = 0; sp < 32; ++sp) {
        const int s0 = sp << 1;
        ITER(s0, bv0);
        ITER(s0 + 1, bv1);
    }
#undef ITER

    // ---- final epilogue (bball[6..7] = layer-3 bias) ----
    if (PHASE == 0) {
        __syncthreads();
#pragma unroll
        for (int m = 0; m < 4; ++m)
#pragma unroll
            for (int j = 0; j < 2; ++j)
#pragma unroll
                for (int reg = 0; reg < 4; ++reg) {
                    const int row = (m << 4) + (kg << 2) + reg;
                    const int col = (w << 5) + (j << 4) + lr;
                    const float h = fmaxf(acc[m][j][reg] + bball[6 + j], 0.f);
                    const float sv = sf32[(((size_t)((tile << 6) + row)) << 9) + col];
                    const int c = (w << 2) + (j << 1) + (lr >> 3);
                    const int slot = (c & 56) | ((c ^ row) & 7);
                    ls[(row << 9) + (slot << 3) + (lr & 7)] = f2bf(sv - h);
                }
        __syncthreads();
#pragma unroll
        for (int c4 = 0; c4 < 4; ++c4) {
            const int row = (c4 << 4) + w;
            const size_t go = (((size_t)((tile << 6) + row)) << 9) + (ac << 3);
            *reinterpret_cast<bf16x8*>(&srel_out[go]) =
                *reinterpret_cast<const bf16x8*>(&ls[(c4 << 13) + (t << 3)]);
        }
        __syncthreads();
#pragma unroll
        for (int m = 0; m < 4; ++m)
#pragma unroll
            for (int j = 0; j < 2; ++j)
#pragma unroll
                for (int reg = 0; reg < 4; ++reg) {
                    const int row = (m << 4) + (kg << 2) + reg;
                    const float h = fmaxf(acc[m][j][reg] + bball[6 + j], 0.f);
                    const int c = (w << 2) + (j << 1) + (lr >> 3);
                    const int slot = (c & 56) | ((c ^ row) & 7);
                    ls[(row << 9) + (slot << 3) + (lr & 7)] = f2bf(h);
                }
        __syncthreads();
#pragma unroll
        for (int c4 = 0; c4 < 4; ++c4) {
            const int row = (c4 << 4) + w;
            const size_t go = (((size_t)((tile << 6) + row)) << 9) + (ac << 3);
            *reinterpret_cast<bf16x8*>(&h_out[go]) =
                *reinterpret_cast<const bf16x8*>(&ls[(c4 << 13) + (t << 3)]);
        }
    } else {
#pragma unroll
        for (int m = 0; m < 4; ++m) {
#pragma unroll
            for (int reg = 0; reg < 4; ++reg) {
                const int row = (m << 4) + (kg << 2) + reg;
                const int pr = perm[(tile << 6) + row];
                if (pr >= 0) {
#pragma unroll
                    for (int j = 0; j < 2; ++j) {
                        const int col = (w << 5) + (j << 4) + lr;
                        const size_t gi = (((size_t)pr) << 9) + col;
                        outf[gi] = acc[m][j][reg] + bball[6 + j] + bf2f(h_in[gi]);
                    }
                }
            }
        }
    }
}

// ---------------- launch ----------------
extern "C" void kernel_launch(void* const* d_in, const int* in_sizes, int n_in,
                              void* d_out, int out_size, void* d_ws, size_t ws_size,
                              hipStream_t stream)
{
    const float* s     = (const float*)d_in[0];
    const int*   y     = (const int*)d_in[1];
    const float* dec_W = (const float*)d_in[2];
    const float* dec_b = (const float*)d_in[3];
    const float* exp_W = (const float*)d_in[4];
    const float* exp_b = (const float*)d_in[5];
    float* out = (float*)d_out;

    unsigned short* Wt   = (unsigned short*)d_ws;               // 36*262144 bf16 (18.9 MB), transposed
    unsigned short* srel = Wt + (size_t)36 * 262144;            // BB*512 bf16 (16 MB)
    unsigned short* hbuf = srel + (size_t)BB * 512;             // BB*512 bf16 (16 MB)
    int* perm     = (int*)(hbuf + (size_t)BB * 512);            // PR2
    int* counts   = perm + PR2;                                 // 8
    int* cursors  = counts + 8;                                 // 8
    int* starts   = cursors + 8;                                // 9
    int* tile_exp = starts + 9;                                 // MAXT2

    cvt_wt<<<4608, 256, 0, stream>>>(dec_W, exp_W, Wt);

    bucket_init<<<(PR2 + 255) / 256, 256, 0, stream>>>(perm, counts, cursors, tile_exp);
    bucket_count<<<BB / 1024, 1024, 0, stream>>>(y, counts);
    bucket_scan<<<1, 64, 0, stream>>>(counts, starts, tile_exp);
    bucket_scatter<<<BB / 1024, 1024, 0, stream>>>(y, starts, cursors, perm);

    fused4<0><<<256, 1024, 0, stream>>>(s, nullptr, Wt, dec_b, srel, hbuf,
                                        nullptr, nullptr, nullptr, nullptr, nullptr);
    fused4<1><<<MAXT2, 1024, 0, stream>>>(nullptr, srel, Wt + ((size_t)4 << 18), exp_b,
                                          nullptr, nullptr, hbuf, out,
                                          perm, tile_exp, starts + 8);
}

// Round 19
// 163.646 us; speedup vs baseline: 1.0589x; 1.0027x over previous
//
#include <hip/hip_runtime.h>
#include <stdint.h>

#define BB 16384
#define PR2 16896     // 16384 + 8*64 worst-case bucket padding (64-granular)
#define MAXT2 264     // PR2/64 = 8*33

typedef short bf16x8 __attribute__((ext_vector_type(8)));
typedef float f32x4 __attribute__((ext_vector_type(4)));

typedef __attribute__((address_space(1))) unsigned short gus_t;
typedef __attribute__((address_space(3))) unsigned short lus_t;

__device__ __forceinline__ unsigned short f2bf(float f) {
    unsigned int u = __float_as_uint(f);
    u += 0x7fffu + ((u >> 16) & 1u);   // RNE
    return (unsigned short)(u >> 16);
}
__device__ __forceinline__ float bf2f(unsigned short h) {
    return __uint_as_float(((unsigned int)h) << 16);
}

__device__ __forceinline__ void gld16(const unsigned short* g, unsigned short* l) {
    __builtin_amdgcn_global_load_lds(
        reinterpret_cast<const gus_t*>(reinterpret_cast<uintptr_t>(g)),
        reinterpret_cast<lus_t*>(reinterpret_cast<uintptr_t>(l)),
        16, 0, 0);
}

#define GLOAD(dst_, ptr_) \
    asm volatile("global_load_dwordx4 %0, %1, off" : "=v"(dst_) : "v"(ptr_) : "memory")

// ---------------- transposing weight conversion ----------------
// Wt[li][ks][col][kg] (16B granules) <- W[li][col][ks*32+kg*8 .. +8]  (f32 -> bf16)
__global__ __launch_bounds__(256) void cvt_wt(const float* __restrict__ dec_W,
                                              const float* __restrict__ exp_W,
                                              unsigned short* __restrict__ dst) {
    const int g = blockIdx.x * 256 + threadIdx.x;   // 36*32768 granules exactly
    const int li = g >> 15;
    const int r = g & 32767;
    const int col = r >> 6;
    const int ks = (r >> 2) & 15;
    const int kg = r & 3;
    const float* src = (li < 4 ? dec_W + ((size_t)li << 18)
                               : exp_W + ((size_t)(li - 4) << 18))
                     + (col << 9) + (ks << 5) + (kg << 3);
    f32x4 v0 = *reinterpret_cast<const f32x4*>(src);
    f32x4 v1 = *reinterpret_cast<const f32x4*>(src + 4);
    bf16x8 o;
#pragma unroll
    for (int q = 0; q < 4; ++q) { o[q] = (short)f2bf(v0[q]); o[q + 4] = (short)f2bf(v1[q]); }
    *reinterpret_cast<bf16x8*>(dst + ((size_t)li << 18) + (ks << 14) + (col << 5) + (kg << 3)) = o;
}

// ---------------- bucketing (64-granular, block-aggregated atomics) ----------------
__global__ void bucket_init(int* perm, int* counts, int* cursors, int* tile_exp) {
    int i = blockIdx.x * blockDim.x + threadIdx.x;
    if (i < PR2) perm[i] = -1;
    if (i < 8) { counts[i] = 0; cursors[i] = 0; }
    if (i < MAXT2) tile_exp[i] = 0;
}

__global__ __launch_bounds__(1024) void bucket_count(const int* __restrict__ y, int* counts) {
    __shared__ int lc[8];
    const int t = threadIdx.x;
    if (t < 8) lc[t] = 0;
    __syncthreads();
    atomicAdd(&lc[y[blockIdx.x * 1024 + t]], 1);
    __syncthreads();
    if (t < 8) atomicAdd(&counts[t], lc[t]);
}

__global__ void bucket_scan(const int* __restrict__ counts, int* starts, int* tile_exp) {
    if (threadIdx.x == 0 && blockIdx.x == 0) {
        int s = 0;
        for (int e = 0; e < 8; ++e) {
            starts[e] = s;
            int nt = (counts[e] + 63) >> 6;
            for (int t = 0; t < nt; ++t) tile_exp[(s >> 6) + t] = e;
            s += nt << 6;
        }
        starts[8] = s;
    }
}

__global__ __launch_bounds__(1024) void bucket_scatter(const int* __restrict__ y,
                                                       const int* __restrict__ starts,
                                                       int* cursors, int* perm) {
    __shared__ int lc[8];
    __shared__ int lbase[8];
    const int t = threadIdx.x;
    if (t < 8) lc[t] = 0;
    __syncthreads();
    const int i = blockIdx.x * 1024 + t;
    const int e = y[i];
    const int r = atomicAdd(&lc[e], 1);
    __syncthreads();
    if (t < 8) lbase[t] = atomicAdd(&cursors[t], lc[t]);
    __syncthreads();
    perm[starts[e] + lbase[e] + r] = i;
}

// ---------------- fused 4-layer MLP: A in LDS (64 KB), W global->VGPR ----------------
// R18 verified base (164.09us). ONE change: per-wave K-stagger removed (off=0) —
// all waves read the same W slice concurrently -> L2 broadcast/hit path instead of
// 16 independent streams per block. Pure address permutation; correctness unchanged.
#define MFMA8(afX, bvX)                                                              \
    acc[0][0] = __builtin_amdgcn_mfma_f32_16x16x32_bf16(afX##0, bvX[0], acc[0][0], 0, 0, 0); \
    acc[0][1] = __builtin_amdgcn_mfma_f32_16x16x32_bf16(afX##0, bvX[1], acc[0][1], 0, 0, 0); \
    acc[1][0] = __builtin_amdgcn_mfma_f32_16x16x32_bf16(afX##1, bvX[0], acc[1][0], 0, 0, 0); \
    acc[1][1] = __builtin_amdgcn_mfma_f32_16x16x32_bf16(afX##1, bvX[1], acc[1][1], 0, 0, 0); \
    acc[2][0] = __builtin_amdgcn_mfma_f32_16x16x32_bf16(afX##2, bvX[0], acc[2][0], 0, 0, 0); \
    acc[2][1] = __builtin_amdgcn_mfma_f32_16x16x32_bf16(afX##2, bvX[1], acc[2][1], 0, 0, 0); \
    acc[3][0] = __builtin_amdgcn_mfma_f32_16x16x32_bf16(afX##3, bvX[0], acc[3][0], 0, 0, 0); \
    acc[3][1] = __builtin_amdgcn_mfma_f32_16x16x32_bf16(afX##3, bvX[1], acc[3][1], 0, 0, 0);

template <int PHASE>
__global__ __launch_bounds__(1024) void fused4(
    const float* __restrict__ sf32,
    const unsigned short* __restrict__ srelg,
    const unsigned short* __restrict__ Wb,      // transposed layout base
    const float* __restrict__ biasb,
    unsigned short* __restrict__ srel_out,
    unsigned short* __restrict__ h_out,
    const unsigned short* __restrict__ h_in,
    float* __restrict__ outf,
    const int* __restrict__ perm,
    const int* __restrict__ tile_exp,
    const int* __restrict__ starts8)
{
    __shared__ __align__(16) unsigned short ls[32768];   // 64 KB: A tile only

    const int bid = blockIdx.x;
    int tile;
    if (PHASE == 0) {
        tile = ((bid & 7) << 5) + (bid >> 3);             // XCD swizzle, 256 = 8*32
    } else {
        tile = (bid & 7) * 33 + (bid >> 3);               // XCD swizzle, 264 = 8*33
        if ((tile << 6) >= starts8[0]) return;
    }

    const unsigned short* Wl;
    const float* bl;
    if (PHASE == 0) { Wl = Wb; bl = biasb; }
    else {
        const int e = tile_exp[tile];
        Wl = Wb + ((size_t)e << 20);                      // e*4*262144 elems
        bl = biasb + (e << 11);
    }

    const int t = threadIdx.x;
    const int w = t >> 6;                                 // 0..15
    const int lane = t & 63;
    const int lr = lane & 15;
    const int kg = lane >> 4;
    const int off = 0;                                    // A/B: K-stagger REMOVED (was (tile*3+w)&15)

    const int ac = (t & 56) | ((t ^ w) & 7);              // A stage src chunk (inv-swizzle)
    const int axor = lr & 7;
    const int arow0 = (lr) << 9;
    const int arow1 = ((16 + lr)) << 9;
    const int arow2 = ((32 + lr)) << 9;
    const int arow3 = ((48 + lr)) << 9;

    // per-lane W fragment base (transposed layout): col*32 + kg*8 elems
    const unsigned short* wpt0 = Wl + ((((w << 5) + lr)) << 5) + (kg << 3);
    const unsigned short* wpt1 = wpt0 + 512;              // col + 16

    // ---- biases for all 4 layers (2 cols/wave-thread) ----
    float bball[8];
#pragma unroll
    for (int l = 0; l < 4; ++l) {
        bball[(l << 1) + 0] = bl[(l << 9) + (w << 5) + lr];
        bball[(l << 1) + 1] = bl[(l << 9) + (w << 5) + 16 + lr];
    }

    // ---- initial A stage ----
    if (PHASE == 0) {
#pragma unroll
        for (int c4 = 0; c4 < 4; ++c4) {
            const int grow = (tile << 6) + (c4 << 4) + w;
            const float* sp = sf32 + (((size_t)grow) << 9) + (ac << 3);
            f32x4 v0 = *reinterpret_cast<const f32x4*>(sp);
            f32x4 v1 = *reinterpret_cast<const f32x4*>(sp + 4);
            bf16x8 o;
#pragma unroll
            for (int q = 0; q < 4; ++q) { o[q] = (short)f2bf(v0[q]); o[q + 4] = (short)f2bf(v1[q]); }
            *reinterpret_cast<bf16x8*>(&ls[(c4 << 13) + (t << 3)]) = o;
        }
    } else {
#pragma unroll
        for (int c4 = 0; c4 < 4; ++c4) {
            int pr = perm[(tile << 6) + (c4 << 4) + w];
            if (pr < 0) pr = 0;
            gld16(srelg + (((size_t)pr) << 9) + (ac << 3), ls + (c4 << 13) + (t << 3));
        }
    }

    // ---- W register prologue: sets for steps 0 and 1 ----
    bf16x8 bv0[2], bv1[2];
    {
        const size_t l0 = ((size_t)(off & 15)) << 14;
        const size_t l1 = ((size_t)((1 + off) & 15)) << 14;
        GLOAD(bv0[0], wpt0 + l0); GLOAD(bv0[1], wpt1 + l0);
        GLOAD(bv1[0], wpt0 + l1); GLOAD(bv1[1], wpt1 + l1);
    }
    if (PHASE == 0) {
        asm volatile("s_waitcnt lgkmcnt(0)" ::: "memory");   // my A ds_writes done
    } else {
        asm volatile("s_waitcnt vmcnt(4)" ::: "memory");     // A DMA done (W still in flight)
    }
    __builtin_amdgcn_s_barrier();                            // A visible to all waves

    f32x4 acc[4][2];
#pragma unroll
    for (int m = 0; m < 4; ++m) { acc[m][0] = f32x4{0,0,0,0}; acc[m][1] = f32x4{0,0,0,0}; }

#define ITER(s_, bvS) do {                                                         \
    if ((s_) < 62) asm volatile("s_waitcnt vmcnt(2)" ::: "memory");                \
    else           asm volatile("s_waitcnt vmcnt(0)" ::: "memory");                \
    __builtin_amdgcn_sched_barrier(0);                                             \
    {                                                                              \
        const int st_ = (((s_) & 15) + off) & 15;                                  \
        const int sb_ = (st_ >> 1) << 6;                                           \
        const int klo_ = ((((st_ & 1) << 2) | kg) ^ axor) << 3;                    \
        bf16x8 af_0 = *reinterpret_cast<const bf16x8*>(&ls[arow0 + sb_ + klo_]);   \
        bf16x8 af_1 = *reinterpret_cast<const bf16x8*>(&ls[arow1 + sb_ + klo_]);   \
        bf16x8 af_2 = *reinterpret_cast<const bf16x8*>(&ls[arow2 + sb_ + klo_]);   \
        bf16x8 af_3 = *reinterpret_cast<const bf16x8*>(&ls[arow3 + sb_ + klo_]);   \
        MFMA8(af_, bvS)                                                            \
    }                                                                              \
    if ((s_) + 2 < 64) {                                                           \
        const size_t lofs_ = (((size_t)(((s_) + 2) >> 4)) << 18)                   \
                           + (((size_t)(((((s_) + 2) & 15) + off) & 15)) << 14);   \
        GLOAD(bvS[0], wpt0 + lofs_);                                               \
        GLOAD(bvS[1], wpt1 + lofs_);                                               \
    }                                                                              \
    if (((s_) & 15) == 15 && (s_) < 63) {                                          \
        __builtin_amdgcn_s_barrier();        /* all waves done reading A */        \
        const int lb_ = ((s_) >> 4) << 1;                                          \
        _Pragma("unroll")                                                          \
        for (int m = 0; m < 4; ++m)                                                \
            _Pragma("unroll")                                                      \
            for (int j = 0; j < 2; ++j) {                                          \
                _Pragma("unroll")                                                  \
                for (int reg = 0; reg < 4; ++reg) {                                \
                    const int row_ = (m << 4) + (kg << 2) + reg;                   \
                    const float v_ = fmaxf(acc[m][j][reg] + bball[lb_ + j], 0.f);  \
                    const int c_ = (w << 2) + (j << 1) + (lr >> 3);                \
                    const int slot_ = (c_ & 56) | ((c_ ^ row_) & 7);               \
                    ls[(row_ << 9) + (slot_ << 3) + (lr & 7)] = f2bf(v_);          \
                }                                                                  \
                acc[m][j] = f32x4{0, 0, 0, 0};                                     \
            }                                                                      \
        asm volatile("s_waitcnt lgkmcnt(0)" ::: "memory");                         \
        __builtin_amdgcn_s_barrier();                                              \
    }                                                                              \
} while (0)

    for (int sp = 0; sp < 32; ++sp) {
        const int s0 = sp << 1;
        ITER(s0, bv0);
        ITER(s0 + 1, bv1);
    }
#undef ITER

    // ---- final epilogue (bball[6..7] = layer-3 bias) ----
    if (PHASE == 0) {
        __syncthreads();
#pragma unroll
        for (int m = 0; m < 4; ++m)
#pragma unroll
            for (int j = 0; j < 2; ++j)
#pragma unroll
                for (int reg = 0; reg < 4; ++reg) {
                    const int row = (m << 4) + (kg << 2) + reg;
                    const int col = (w << 5) + (j << 4) + lr;
                    const float h = fmaxf(acc[m][j][reg] + bball[6 + j], 0.f);
                    const float sv = sf32[(((size_t)((tile << 6) + row)) << 9) + col];
                    const int c = (w << 2) + (j << 1) + (lr >> 3);
                    const int slot = (c & 56) | ((c ^ row) & 7);
                    ls[(row << 9) + (slot << 3) + (lr & 7)] = f2bf(sv - h);
                }
        __syncthreads();
#pragma unroll
        for (int c4 = 0; c4 < 4; ++c4) {
            const int row = (c4 << 4) + w;
            const size_t go = (((size_t)((tile << 6) + row)) << 9) + (ac << 3);
            *reinterpret_cast<bf16x8*>(&srel_out[go]) =
                *reinterpret_cast<const bf16x8*>(&ls[(c4 << 13) + (t << 3)]);
        }
        __syncthreads();
#pragma unroll
        for (int m = 0; m < 4; ++m)
#pragma unroll
            for (int j = 0; j < 2; ++j)
#pragma unroll
                for (int reg = 0; reg < 4; ++reg) {
                    const int row = (m << 4) + (kg << 2) + reg;
                    const float h = fmaxf(acc[m][j][reg] + bball[6 + j], 0.f);
                    const int c = (w << 2) + (j << 1) + (lr >> 3);
                    const int slot = (c & 56) | ((c ^ row) & 7);
                    ls[(row << 9) + (slot << 3) + (lr & 7)] = f2bf(h);
                }
        __syncthreads();
#pragma unroll
        for (int c4 = 0; c4 < 4; ++c4) {
            const int row = (c4 << 4) + w;
            const size_t go = (((size_t)((tile << 6) + row)) << 9) + (ac << 3);
            *reinterpret_cast<bf16x8*>(&h_out[go]) =
                *reinterpret_cast<const bf16x8*>(&ls[(c4 << 13) + (t << 3)]);
        }
    } else {
#pragma unroll
        for (int m = 0; m < 4; ++m) {
#pragma unroll
            for (int reg = 0; reg < 4; ++reg) {
                const int row = (m << 4) + (kg << 2) + reg;
                const int pr = perm[(tile << 6) + row];
                if (pr >= 0) {
#pragma unroll
                    for (int j = 0; j < 2; ++j) {
                        const int col = (w << 5) + (j << 4) + lr;
                        const size_t gi = (((size_t)pr) << 9) + col;
                        outf[gi] = acc[m][j][reg] + bball[6 + j] + bf2f(h_in[gi]);
                    }
                }
            }
        }
    }
}

// ---------------- launch ----------------
extern "C" void kernel_launch(void* const* d_in, const int* in_sizes, int n_in,
                              void* d_out, int out_size, void* d_ws, size_t ws_size,
                              hipStream_t stream)
{
    const float* s     = (const float*)d_in[0];
    const int*   y     = (const int*)d_in[1];
    const float* dec_W = (const float*)d_in[2];
    const float* dec_b = (const float*)d_in[3];
    const float* exp_W = (const float*)d_in[4];
    const float* exp_b = (const float*)d_in[5];
    float* out = (float*)d_out;

    unsigned short* Wt   = (unsigned short*)d_ws;               // 36*262144 bf16 (18.9 MB), transposed
    unsigned short* srel = Wt + (size_t)36 * 262144;            // BB*512 bf16 (16 MB)
    unsigned short* hbuf = srel + (size_t)BB * 512;             // BB*512 bf16 (16 MB)
    int* perm     = (int*)(hbuf + (size_t)BB * 512);            // PR2
    int* counts   = perm + PR2;                                 // 8
    int* cursors  = counts + 8;                                 // 8
    int* starts   = cursors + 8;                                // 9
    int* tile_exp = starts + 9;                                 // MAXT2

    cvt_wt<<<4608, 256, 0, stream>>>(dec_W, exp_W, Wt);

    bucket_init<<<(PR2 + 255) / 256, 256, 0, stream>>>(perm, counts, cursors, tile_exp);
    bucket_count<<<BB / 1024, 1024, 0, stream>>>(y, counts);
    bucket_scan<<<1, 64, 0, stream>>>(counts, starts, tile_exp);
    bucket_scatter<<<BB / 1024, 1024, 0, stream>>>(y, starts, cursors, perm);

    fused4<0><<<256, 1024, 0, stream>>>(s, nullptr, Wt, dec_b, srel, hbuf,
                                        nullptr, nullptr, nullptr, nullptr, nullptr);
    fused4<1><<<MAXT2, 1024, 0, stream>>>(nullptr, srel, Wt + ((size_t)4 << 18), exp_b,
                                          nullptr, nullptr, hbuf, out,
                                          perm, tile_exp, starts + 8);
}